// Round 15
// baseline (139.555 us; speedup 1.0000x reference)
//
#include <hip/hip_runtime.h>
#include <math.h>

// SocialPooling: B=8, N=8192, D=64.
// w_ij = exp(-d2/50) if sqrt(max(d2,1e-12)) <= 10 else 0;
// keep w >= (32nd largest w in row); normalize by clip(row_sum,1e-8);
// out[b,i,d] = sum_j w_ij * F[b,j,d].
//
// R15. R14 falsified byte-BW-bound pool (bf16 halved bytes, main unchanged).
// R11/R12: pool ~37us at 25% AND 100% occupancy, any layout => the random
// global-gather path is structurally slow per-request. Fix: REMOVE it.
//  - k_pool_cell: block=(cell,batch,dhalf), 1600 blocks x 1024 thr. Stage the
//    3x3-cell neighborhood's bf16 features (<=896 pos x 64B = 56KB) in LDS,
//    coalesced; 16 waves pool the cell's ~82 rows from LDS (ds_read_u16,
//    <=2-way conflicts = free). Global traffic -> sequential streams.
//  - k_select: R10's proven kernel (16.4us, selection bit-identical since
//    R6); pad-p now = first-range start (maps to LDS slot 0, w=0).
//  - k_convert: R14's proven bf16 binned layout FB[p][b][d].
// Fallback (uniform, per block) to global bf16 gather if neighborhood > 896.

constexpr int   NCELL  = 10;
constexpr int   NCELL2 = 100;
constexpr int   MAXC   = 416;   // candidates/row: lambda~257, std~16 (+10σ)
constexpr int   MAXK   = 64;    // kept: 32 + boundary ties
constexpr int   MAXNB  = 896;   // neighborhood cap: lambda~737, +5.9σ
constexpr float BUCKSC = 2.56f; // d2 in [0,100] -> bucket 0..255 (monotone)
constexpr int   NXCD   = 8;

__device__ __forceinline__ int cell_x(float x) {
    int c = (int)(x * 0.09765625f);   // 1/10.24 exact in f32
    return min(max(c, 0), NCELL - 1);
}
__device__ __forceinline__ int cell_of(float2 c) {
    return cell_x(c.y) * NCELL + cell_x(c.x);
}

// RNE f32 -> bf16 (features are finite normals)
__device__ __forceinline__ unsigned short f2bf(float f) {
    unsigned int x = __float_as_uint(f);
    return (unsigned short)((x + 0x7FFFu + ((x >> 16) & 1u)) >> 16);
}

// wave-synchronous LDS handoff (LDS is wave-private: drain lgkmcnt only)
__device__ __forceinline__ void wsync() {
    __builtin_amdgcn_wave_barrier();
    asm volatile("s_waitcnt lgkmcnt(0)" ::: "memory");
    __builtin_amdgcn_wave_barrier();
}

// ---- fused prep: zero + count + parallel scan + scatter, one block ----
__global__ __launch_bounds__(1024)
void k_prep(const float* __restrict__ C, int* __restrict__ cellStart,
            float2* __restrict__ bXY, int* __restrict__ bIdx, int N)
{
    __shared__ int h[128];
    __shared__ int cur[NCELL2];
    const int t = threadIdx.x;
    if (t < 128) h[t] = 0;
    __syncthreads();
    const float2* C2 = (const float2*)C;
    for (int j = t; j < N; j += 1024) atomicAdd(&h[cell_of(C2[j])], 1);
    __syncthreads();
    #pragma unroll
    for (int o = 1; o < 128; o <<= 1) {
        int u = (t < 128 && t >= o) ? h[t - o] : 0;
        __syncthreads();
        if (t < 128) h[t] += u;
        __syncthreads();
    }
    if (t < NCELL2) {
        int s = (t == 0) ? 0 : h[t - 1];
        cur[t] = s; cellStart[t] = s;
        if (t == 0) cellStart[NCELL2] = h[NCELL2 - 1];
    }
    __syncthreads();
    for (int j = t; j < N; j += 1024) {
        float2 c = C2[j];
        int pos = atomicAdd(&cur[cell_of(c)], 1);
        bXY[pos] = c; bIdx[pos] = j;
    }
}

// ---- bf16 binned convert: FB[p][b][d] = bf16(F[b][bIdx[p]][d]) (R14) ----
__global__ __launch_bounds__(256)
void k_convert(const float* __restrict__ F, const int* __restrict__ bIdx,
               unsigned short* __restrict__ FB, int N)
{
    const int tid = blockIdx.x * 256 + threadIdx.x;
    const int dg = tid & 7;
    const int b  = (tid >> 3) & 7;
    const int p  = tid >> 6;
    const int j  = bIdx[p];                       // uniform per 64 tids
    const float* src = F + ((size_t)b * N + (size_t)j) * 64 + dg * 8;
    const float4 v0 = *(const float4*)src;
    const float4 v1 = *(const float4*)(src + 4);
    union { unsigned short u[8]; uint4 q; } pk;
    pk.u[0] = f2bf(v0.x); pk.u[1] = f2bf(v0.y);
    pk.u[2] = f2bf(v0.z); pk.u[3] = f2bf(v0.w);
    pk.u[4] = f2bf(v1.x); pk.u[5] = f2bf(v1.y);
    pk.u[6] = f2bf(v1.z); pk.u[7] = f2bf(v1.w);
    *(uint4*)(FB + (size_t)p * 512 + b * 64 + dg * 8) = pk.q;
}

// ---- selection: passes 1-3 bit-identical to R6..R14; writes (w,p) lists.
//      Pad entries: w=0, p=first-neighborhood-range start (LDS slot 0). ----
__global__ __launch_bounds__(256, 8)
void k_select(const float2* __restrict__ bXY,
              const int* __restrict__ bIdx,
              const int* __restrict__ cellStart,
              float2* __restrict__ kv,       // [N][MAXK] (w, bitcast p)
              int2* __restrict__ kn,         // [N] (Kpad, original i)
              int N)
{
    __shared__ float  s_cd2[4][MAXC];
    __shared__ int    s_cjj[4][MAXC];
    __shared__ __align__(16) int s_hist[4][256];
    __shared__ float  s_blist[4][32];
    __shared__ float2 s_kwj[4][MAXK];

    const int t = threadIdx.x, wid = t >> 6, lane = t & 63;
    float*  cd2   = s_cd2[wid];
    int*    cjj   = s_cjj[wid];
    int*    hist  = s_hist[wid];
    float*  blist = s_blist[wid];
    float2* kwj   = s_kwj[wid];

    *(int4*)&hist[lane * 4] = make_int4(0, 0, 0, 0);

    const int bid = blockIdx.x, nb = gridDim.x;
    const int sb = (nb % NXCD == 0) ? (bid % NXCD) * (nb / NXCD) + bid / NXCD : bid;
    const int q = sb * 4 + wid;
    if (q >= N) return;

    const float2 ci = bXY[q];
    const int    i  = bIdx[q];
    const int cx = cell_x(ci.x), cy = cell_x(ci.y);
    const unsigned long long below = (1ull << lane) - 1ull;

    // pass 1: scan 3x3 cells; ballot+popc compaction; store position p
    int mc = 0;
    for (int ry = max(cy - 1, 0); ry <= min(cy + 1, NCELL - 1); ++ry) {
        const int c0 = ry * NCELL + max(cx - 1, 0);
        const int c1 = ry * NCELL + min(cx + 1, NCELL - 1);
        const int s = cellStart[c0], e = cellStart[c1 + 1];
        for (int p0 = s; p0 < e; p0 += 64) {
            const int p = p0 + lane;
            bool hit = false; float d2 = 0.0f;
            if (p < e) {
                float2 cp = bXY[p];
                float dx = ci.x - cp.x, dy = ci.y - cp.y;
                d2 = dx * dx + dy * dy;
                float d = sqrtf(fmaxf(d2, 1e-12f));   // exact ref boundary
                hit = (d <= 10.0f);
            }
            unsigned long long mk = __ballot(hit);
            int off = __popcll(mk & below);
            if (hit && mc + off < MAXC) { cd2[mc + off] = d2; cjj[mc + off] = p; }
            mc += (int)__popcll(mk);
        }
    }
    wsync();
    const int M = min(mc, MAXC);

    // pass 2: 32nd-smallest d2 via per-wave 256-bin histogram
    float thr_d2, thr_w;
    if (M > 32) {
        for (int k = lane; k < M; k += 64)
            atomicAdd(&hist[min(255, (int)(cd2[k] * BUCKSC))], 1);
        wsync();
        int4 h4 = *(const int4*)&hist[lane * 4];
        int hh0 = h4.x, hh1 = h4.y, hh2 = h4.z, hh3 = h4.w;
        int tot = hh0 + hh1 + hh2 + hh3;
        int sc = tot;
        #pragma unroll
        for (int o = 1; o < 64; o <<= 1) {
            int v = __shfl_up(sc, o);
            if (lane >= o) sc += v;
        }
        int ce = sc - tot;
        int fb = -1, fce = 0;
        if (ce <= 31 && 31 < ce + hh0) { fb = lane * 4 + 0; fce = ce; } ce += hh0;
        if (fb < 0 && ce <= 31 && 31 < ce + hh1) { fb = lane * 4 + 1; fce = ce; } ce += hh1;
        if (fb < 0 && ce <= 31 && 31 < ce + hh2) { fb = lane * 4 + 2; fce = ce; } ce += hh2;
        if (fb < 0 && ce <= 31 && 31 < ce + hh3) { fb = lane * 4 + 3; fce = ce; }
        unsigned long long mk1 = __ballot(fb >= 0);
        int src1 = (mk1 != 0ull) ? (__ffsll((unsigned long long)mk1) - 1) : 0;
        const int bstar   = __shfl(fb,  src1);
        const int cumexcl = __shfl(fce, src1);
        int bn = 0;
        for (int k0 = 0; k0 < M; k0 += 64) {
            const int k = k0 + lane;
            bool inb = (k < M) && (min(255, (int)(cd2[k] * BUCKSC)) == bstar);
            unsigned long long mk = __ballot(inb);
            int off = __popcll(mk & below);
            if (inb && bn + off < 32) blist[bn + off] = cd2[k];
            bn += (int)__popcll(mk);
        }
        wsync();
        bn = min(bn, 32);
        float mine = 0.0f; int ok = 0;
        if (lane < bn) {
            mine = blist[lane];
            int cl = 0, ceq = 0;
            for (int m = 0; m < bn; ++m) {
                cl  += (blist[m] <  mine);
                ceq += (blist[m] == mine);
            }
            int r = cumexcl + cl;
            ok = (r <= 31 && 31 < r + ceq);
        }
        unsigned long long mk2 = __ballot(ok);
        int src2 = (mk2 != 0ull) ? (__ffsll((unsigned long long)mk2) - 1) : 0;
        thr_d2 = __shfl(mine, src2);
        thr_w  = expf(-(thr_d2 / 50.0f));
    } else {
        thr_d2 = 3.4e38f;
        thr_w  = 0.0f;
    }

    // pass 3: keep w >= thr_w over d2-margin superset (tie-exact); store p
    const float marg = thr_d2 + 1e-4f;
    int kc = 0;
    for (int k0 = 0; k0 < M; k0 += 64) {
        const int k = k0 + lane;
        bool keep = false; float w = 0.0f; int jj = 0;
        if (k < M && cd2[k] <= marg) {
            w = expf(-(cd2[k] / 50.0f));
            if (w >= thr_w) { keep = true; jj = cjj[k]; }
        }
        unsigned long long mk = __ballot(keep);
        int off = __popcll(mk & below);
        if (keep && kc + off < MAXK)
            kwj[kc + off] = make_float2(w, __int_as_float(jj));
        kc += (int)__popcll(mk);
    }
    wsync();
    const int K = min(kc, MAXK);

    // normalize in registers; lane l holds pair l
    float2 pr = make_float2(0.0f, 0.0f);
    if (lane < K) pr = kwj[lane];
    float v = pr.x;
    #pragma unroll
    for (int o = 32; o > 0; o >>= 1) v += __shfl_xor(v, o);
    const float ssum = fmaxf(v, 1e-8f);
    const float wn = pr.x / ssum;

    // pad p = first neighborhood range start (maps to LDS slot 0; w=0)
    const int pPad = cellStart[max(cy - 1, 0) * NCELL + max(cx - 1, 0)];
    kv[(size_t)q * MAXK + lane] =
        (lane < K) ? make_float2(wn, pr.y) : make_float2(0.0f, __int_as_float(pPad));
    if (lane == 0) kn[q] = make_int2((K + 3) & ~3, i);
}

// ---- per-cell LDS pooling: block = (cell, batch, dim-half) ----
// Stage neighborhood bf16 (<=896 x 32 dims = 56KB) in LDS; 16 waves pool the
// cell's rows from LDS. 2 blocks/CU (112KB LDS) = 32 waves/CU.
__global__ __launch_bounds__(1024, 8)
void k_pool_cell(const unsigned short* __restrict__ FB,
                 const float2* __restrict__ kv,
                 const int2* __restrict__ kn,
                 const int* __restrict__ cellStart,
                 float* __restrict__ out, int N)
{
    __shared__ unsigned short feat[MAXNB * 32];

    const int bid  = blockIdx.x;
    const int cell = bid >> 4;
    const int b    = (bid >> 1) & 7;
    const int h    = bid & 1;
    const int cx = cell % NCELL, cy = cell / NCELL;
    const int x0 = max(cx - 1, 0), x1 = min(cx + 1, NCELL - 1);
    const int ry0 = max(cy - 1, 0), ry1 = min(cy + 1, NCELL - 1);

    int rs[3], re[3], rb[3];
    int nr = 0, nbt = 0;
    for (int ry = ry0; ry <= ry1; ++ry) {
        rs[nr] = cellStart[ry * NCELL + x0];
        re[nr] = cellStart[ry * NCELL + x1 + 1];
        rb[nr] = nbt;
        nbt += re[nr] - rs[nr];
        ++nr;
    }
    for (int r = nr; r < 3; ++r) { rs[r] = 0x3FFFFFFF; re[r] = 0x3FFFFFFF; rb[r] = 0; }

    const int t = threadIdx.x;
    const bool fits = (nbt <= MAXNB);   // uniform

    if (fits) {
        // stage: per position 64B = 4 x 16B chunks; coalesced uint4
        for (int r = 0; r < nr; ++r) {
            const int s = rs[r], len = re[r] - s, base = rb[r];
            for (int u = t; u < len * 4; u += 1024) {
                const int pos = u >> 2;
                const int c8  = (u & 3) * 8;       // short offset in 64B row
                const uint4 v = *(const uint4*)(FB + (size_t)(s + pos) * 512
                                                + b * 64 + h * 32 + c8);
                *(uint4*)(feat + (base + pos) * 32 + c8) = v;
            }
        }
    }
    __syncthreads();

    const int wave = t >> 6, lane = t & 63;
    const int d    = lane & 31;          // dim within half
    const int ksub = lane >> 5;          // 0: even k, 1: odd k
    const int rowS = cellStart[cell], rowE = cellStart[cell + 1];

    for (int q = rowS + wave; q < rowE; q += 16) {
        const int2 kni = kn[q];
        const int Kp = kni.x;            // multiple of 4; pad w=0, p->slot 0
        const int i  = kni.y;            // original row index
        const float2 prl = kv[(size_t)q * MAXK + lane];
        const int wi = __float_as_int(prl.x);
        const int pi = __float_as_int(prl.y);

        float a = 0.0f;
        for (int k = 0; k < Kp; k += 2) {
            const int   pe = __builtin_amdgcn_readlane(pi, k);
            const int   po = __builtin_amdgcn_readlane(pi, k + 1);
            const float we = __int_as_float(__builtin_amdgcn_readlane(wi, k));
            const float wo = __int_as_float(__builtin_amdgcn_readlane(wi, k + 1));
            const float w  = ksub ? wo : we;
            float f;
            if (fits) {
                // scalar 3-range map p -> LDS slot (ranges are ordered)
                const int le = (pe < re[0]) ? (pe - rs[0])
                             : (pe < re[1]) ? (pe - rs[1] + rb[1])
                                            : (pe - rs[2] + rb[2]);
                const int lo = (po < re[0]) ? (po - rs[0])
                             : (po < re[1]) ? (po - rs[1] + rb[1])
                                            : (po - rs[2] + rb[2]);
                const int loc = ksub ? lo : le;
                const unsigned short us = feat[loc * 32 + d];
                f = __uint_as_float((unsigned)us << 16);
            } else {
                const int p = ksub ? po : pe;
                const unsigned short us = FB[(size_t)p * 512 + b * 64 + h * 32 + d];
                f = __uint_as_float((unsigned)us << 16);
            }
            a += w * f;
        }
        a += __shfl_xor(a, 32);          // fold odd-k partial into even half
        if (lane < 32)
            out[((size_t)b * N + (size_t)i) * 64 + h * 32 + d] = a;
    }
}

// ---- generic fallback (R9's fused kernel, original-F f32 gather) ----
__global__ __launch_bounds__(256, 8)
void social_pool_fused(const float* __restrict__ F,
                       const float2* __restrict__ bXY,
                       const int* __restrict__ bIdx,
                       const int* __restrict__ cellStart,
                       float* __restrict__ out, int N, int B)
{
    __shared__ float  s_cd2[4][MAXC];
    __shared__ int    s_cjj[4][MAXC];
    __shared__ __align__(16) int s_hist[4][256];
    __shared__ float  s_blist[4][32];
    __shared__ float2 s_kwj[4][MAXK];

    const int t = threadIdx.x, wid = t >> 6, lane = t & 63;
    float*  cd2   = s_cd2[wid];
    int*    cjj   = s_cjj[wid];
    int*    hist  = s_hist[wid];
    float*  blist = s_blist[wid];
    float2* kwj   = s_kwj[wid];

    *(int4*)&hist[lane * 4] = make_int4(0, 0, 0, 0);

    const int bid = blockIdx.x, nb = gridDim.x;
    const int sb = (nb % NXCD == 0) ? (bid % NXCD) * (nb / NXCD) + bid / NXCD : bid;
    const int q = sb * 4 + wid;
    if (q >= N) return;

    const float2 ci = bXY[q];
    const int    i  = bIdx[q];
    const int cx = cell_x(ci.x), cy = cell_x(ci.y);
    const unsigned long long below = (1ull << lane) - 1ull;

    int mc = 0;
    for (int ry = max(cy - 1, 0); ry <= min(cy + 1, NCELL - 1); ++ry) {
        const int c0 = ry * NCELL + max(cx - 1, 0);
        const int c1 = ry * NCELL + min(cx + 1, NCELL - 1);
        const int s = cellStart[c0], e = cellStart[c1 + 1];
        for (int p0 = s; p0 < e; p0 += 64) {
            const int p = p0 + lane;
            bool hit = false; float d2 = 0.0f;
            if (p < e) {
                float2 cp = bXY[p];
                float dx = ci.x - cp.x, dy = ci.y - cp.y;
                d2 = dx * dx + dy * dy;
                float d = sqrtf(fmaxf(d2, 1e-12f));
                hit = (d <= 10.0f);
            }
            unsigned long long mk = __ballot(hit);
            int off = __popcll(mk & below);
            if (hit && mc + off < MAXC) { cd2[mc + off] = d2; cjj[mc + off] = p; }
            mc += (int)__popcll(mk);
        }
    }
    wsync();
    const int M = min(mc, MAXC);

    float thr_d2, thr_w;
    if (M > 32) {
        for (int k = lane; k < M; k += 64)
            atomicAdd(&hist[min(255, (int)(cd2[k] * BUCKSC))], 1);
        wsync();
        int4 h4 = *(const int4*)&hist[lane * 4];
        int hh0 = h4.x, hh1 = h4.y, hh2 = h4.z, hh3 = h4.w;
        int tot = hh0 + hh1 + hh2 + hh3;
        int sc = tot;
        #pragma unroll
        for (int o = 1; o < 64; o <<= 1) {
            int v = __shfl_up(sc, o);
            if (lane >= o) sc += v;
        }
        int ce = sc - tot;
        int fb = -1, fce = 0;
        if (ce <= 31 && 31 < ce + hh0) { fb = lane * 4 + 0; fce = ce; } ce += hh0;
        if (fb < 0 && ce <= 31 && 31 < ce + hh1) { fb = lane * 4 + 1; fce = ce; } ce += hh1;
        if (fb < 0 && ce <= 31 && 31 < ce + hh2) { fb = lane * 4 + 2; fce = ce; } ce += hh2;
        if (fb < 0 && ce <= 31 && 31 < ce + hh3) { fb = lane * 4 + 3; fce = ce; }
        unsigned long long mk1 = __ballot(fb >= 0);
        int src1 = (mk1 != 0ull) ? (__ffsll((unsigned long long)mk1) - 1) : 0;
        const int bstar   = __shfl(fb,  src1);
        const int cumexcl = __shfl(fce, src1);
        int bn = 0;
        for (int k0 = 0; k0 < M; k0 += 64) {
            const int k = k0 + lane;
            bool inb = (k < M) && (min(255, (int)(cd2[k] * BUCKSC)) == bstar);
            unsigned long long mk = __ballot(inb);
            int off = __popcll(mk & below);
            if (inb && bn + off < 32) blist[bn + off] = cd2[k];
            bn += (int)__popcll(mk);
        }
        wsync();
        bn = min(bn, 32);
        float mine = 0.0f; int ok = 0;
        if (lane < bn) {
            mine = blist[lane];
            int cl = 0, ceq = 0;
            for (int m = 0; m < bn; ++m) {
                cl  += (blist[m] <  mine);
                ceq += (blist[m] == mine);
            }
            int r = cumexcl + cl;
            ok = (r <= 31 && 31 < r + ceq);
        }
        unsigned long long mk2 = __ballot(ok);
        int src2 = (mk2 != 0ull) ? (__ffsll((unsigned long long)mk2) - 1) : 0;
        thr_d2 = __shfl(mine, src2);
        thr_w  = expf(-(thr_d2 / 50.0f));
    } else {
        thr_d2 = 3.4e38f;
        thr_w  = 0.0f;
    }

    const float marg = thr_d2 + 1e-4f;
    int kc = 0;
    for (int k0 = 0; k0 < M; k0 += 64) {
        const int k = k0 + lane;
        bool keep = false; float w = 0.0f; int jj = 0;
        if (k < M && cd2[k] <= marg) {
            w = expf(-(cd2[k] / 50.0f));
            if (w >= thr_w) { keep = true; jj = bIdx[cjj[k]]; }
        }
        unsigned long long mk = __ballot(keep);
        int off = __popcll(mk & below);
        if (keep && kc + off < MAXK)
            kwj[kc + off] = make_float2(w, __int_as_float(jj));
        kc += (int)__popcll(mk);
    }
    wsync();
    const int K = min(kc, MAXK);

    float2 pr = make_float2(0.0f, 0.0f);
    if (lane < K) pr = kwj[lane];
    float v = pr.x;
    #pragma unroll
    for (int o = 32; o > 0; o >>= 1) v += __shfl_xor(v, o);
    const float ssum = fmaxf(v, 1e-8f);
    const float wn = pr.x / ssum;
    const int   jn = __float_as_int(pr.y);
    const int   wi = __float_as_int(wn);

    const size_t NL = (size_t)N * 64;
    const float* F0 = F + lane;
    float* O0 = out + (size_t)i * 64 + lane;
    for (int b = 0; b < B; ++b) {
        float a = 0.0f;
        const float* Fb = F0 + (size_t)b * NL;
        for (int k = 0; k < K; ++k) {
            const float w = __int_as_float(__builtin_amdgcn_readlane(wi, k));
            const size_t o = (size_t)__builtin_amdgcn_readlane(jn, k) * 64;
            a += w * Fb[o];
        }
        O0[(size_t)b * NL] = a;
    }
}

extern "C" void kernel_launch(void* const* d_in, const int* in_sizes, int n_in,
                              void* d_out, int out_size, void* d_ws, size_t ws_size,
                              hipStream_t stream)
{
    const float* F = (const float*)d_in[0];   // features [B,N,64] f32
    const float* C = (const float*)d_in[1];   // coordinates [N,2] f32
    float* out = (float*)d_out;               // [B,N,64] f32

    const int N = in_sizes[1] / 2;            // 8192
    const int B = in_sizes[0] / (N * 64);     // 8

    // d_ws layout: cellStart | bXY | bIdx | kn | kv | (256-aligned) FB bf16
    char* ws = (char*)d_ws;
    int*    cellStart = (int*)(ws + 0);                        // 512 B
    float2* bXY       = (float2*)(ws + 512);                   // N*8
    int*    bIdx      = (int*)(ws + 512 + (size_t)N * 8);      // N*4
    size_t  off       = 512 + (size_t)N * 8 + (size_t)N * 4;
    off = (off + 15) & ~(size_t)15;
    int2*   kn        = (int2*)(ws + off);   off += (size_t)N * 8;
    float2* kv        = (float2*)(ws + off); off += (size_t)N * MAXK * 8;
    off = (off + 255) & ~(size_t)255;
    unsigned short* FB = (unsigned short*)(ws + off);
    const size_t needFast = off + (size_t)N * B * 64 * sizeof(unsigned short);

    k_prep<<<1, 1024, 0, stream>>>(C, cellStart, bXY, bIdx, N);

    if (N == 8192 && B == 8 && ws_size >= needFast) {
        k_convert  <<<2048, 256, 0, stream>>>(F, bIdx, FB, N);
        k_select   <<<2048, 256, 0, stream>>>(bXY, bIdx, cellStart, kv, kn, N);
        k_pool_cell<<<NCELL2 * 16, 1024, 0, stream>>>(FB, kv, kn, cellStart, out, N);
    } else {
        social_pool_fused<<<(N + 3) / 4, 256, 0, stream>>>(
            F, bXY, bIdx, cellStart, out, N, B);
    }
}

// Round 16
// 51.063 us; speedup vs baseline: 2.7330x; 2.7330x over previous
//
#include <hip/hip_runtime.h>
#include <math.h>

// SocialPooling: B=8, N=8192, D=64.
// w_ij = exp(-d2/50) if sqrt(max(d2,1e-12)) <= 10 else 0;
// keep w >= (32nd largest w in row); normalize by clip(row_sum,1e-8);
// out[b,i,d] = sum_j w_ij * F[b,j,d].
//
// R16: RESTORE R8 (best measured: 50.7us total, main 45.9). Ten pool-phase
// experiments (R9-R15) all null or regression: the ~37us gather phase is
// invariant to bytes (bf16), occupancy (25% vs 100%), layout (3 permutes),
// loop order, LDS staging (2x), and L2 windowing (2x). ~14TB/s is what the
// machine gives this cached-gather pattern. R8's fused select+pool overlaps
// select (~16us) under it; prep ~2.5; total ~50 is the practical floor of
// this decomposition. Only change vs R8: unroll 4 on pass-4 k-loop
// (accumulation order per output element unchanged -> bit-identical).

constexpr int   NCELL  = 10;
constexpr int   NCELL2 = 100;
constexpr int   MAXC   = 416;   // candidates/row: lambda~257, std~16 (+10σ)
constexpr int   MAXK   = 64;    // kept: 32 + boundary ties
constexpr float BUCKSC = 2.56f; // d2 in [0,100] -> bucket 0..255 (monotone)
constexpr int   NXCD   = 8;

__device__ __forceinline__ int cell_x(float x) {
    int c = (int)(x * 0.09765625f);   // 1/10.24 exact in f32
    return min(max(c, 0), NCELL - 1);
}
__device__ __forceinline__ int cell_of(float2 c) {
    return cell_x(c.y) * NCELL + cell_x(c.x);
}

// wave-synchronous LDS handoff (LDS is wave-private: drain lgkmcnt only)
__device__ __forceinline__ void wsync() {
    __builtin_amdgcn_wave_barrier();
    asm volatile("s_waitcnt lgkmcnt(0)" ::: "memory");
    __builtin_amdgcn_wave_barrier();
}

// ---- fused prep: zero + count + parallel scan + scatter, one block ----
__global__ __launch_bounds__(1024)
void k_prep(const float* __restrict__ C, int* __restrict__ cellStart,
            float2* __restrict__ bXY, int* __restrict__ bIdx, int N)
{
    __shared__ int h[128];
    __shared__ int cur[NCELL2];
    const int t = threadIdx.x;
    if (t < 128) h[t] = 0;
    __syncthreads();
    const float2* C2 = (const float2*)C;
    for (int j = t; j < N; j += 1024) atomicAdd(&h[cell_of(C2[j])], 1);
    __syncthreads();
    #pragma unroll
    for (int o = 1; o < 128; o <<= 1) {
        int u = (t < 128 && t >= o) ? h[t - o] : 0;
        __syncthreads();
        if (t < 128) h[t] += u;
        __syncthreads();
    }
    if (t < NCELL2) {
        int s = (t == 0) ? 0 : h[t - 1];
        cur[t] = s; cellStart[t] = s;
        if (t == 0) cellStart[NCELL2] = h[NCELL2 - 1];
    }
    __syncthreads();
    for (int j = t; j < N; j += 1024) {
        float2 c = C2[j];
        int pos = atomicAdd(&cur[cell_of(c)], 1);
        bXY[pos] = c; bIdx[pos] = j;
    }
}

// ---- fused main (R8): one wave per row, 4 rows/block, 19968 B LDS ----
template<int TN, int TB>
__global__ __launch_bounds__(256, 8)   // pin VGPR<=64 => 8 blocks/CU
void social_pool_fused(const float* __restrict__ F,
                       const float2* __restrict__ bXY,
                       const int* __restrict__ bIdx,
                       const int* __restrict__ cellStart,
                       float* __restrict__ out, int Nrt, int Brt)
{
    const int N = (TN > 0) ? TN : Nrt;
    const int B = (TB > 0) ? TB : Brt;

    __shared__ float  s_cd2[4][MAXC];
    __shared__ int    s_cjj[4][MAXC];
    __shared__ __align__(16) int s_hist[4][256];
    __shared__ float  s_blist[4][32];
    __shared__ float2 s_kwj[4][MAXK];

    const int t = threadIdx.x, wid = t >> 6, lane = t & 63;
    float*  cd2   = s_cd2[wid];
    int*    cjj   = s_cjj[wid];
    int*    hist  = s_hist[wid];
    float*  blist = s_blist[wid];
    float2* kwj   = s_kwj[wid];

    *(int4*)&hist[lane * 4] = make_int4(0, 0, 0, 0);

    // XCD-chunked swizzle (bijective: nb % 8 == 0)
    const int bid = blockIdx.x, nb = gridDim.x;
    const int sb = (nb % NXCD == 0) ? (bid % NXCD) * (nb / NXCD) + bid / NXCD : bid;
    const int q = sb * 4 + wid;
    if (q >= N) return;

    const float2 ci = bXY[q];
    const int    i  = bIdx[q];          // original row index for output
    const int cx = cell_x(ci.x), cy = cell_x(ci.y);
    const unsigned long long below = (1ull << lane) - 1ull;

    // pass 1: scan 3x3 cells; ballot+popc compaction; store position p
    int mc = 0;
    for (int ry = max(cy - 1, 0); ry <= min(cy + 1, NCELL - 1); ++ry) {
        const int c0 = ry * NCELL + max(cx - 1, 0);
        const int c1 = ry * NCELL + min(cx + 1, NCELL - 1);
        const int s = cellStart[c0], e = cellStart[c1 + 1];
        for (int p0 = s; p0 < e; p0 += 64) {
            const int p = p0 + lane;
            bool hit = false; float d2 = 0.0f;
            if (p < e) {
                float2 cp = bXY[p];
                float dx = ci.x - cp.x, dy = ci.y - cp.y;
                d2 = dx * dx + dy * dy;
                float d = sqrtf(fmaxf(d2, 1e-12f));   // exact ref boundary
                hit = (d <= 10.0f);
            }
            unsigned long long mk = __ballot(hit);
            int off = __popcll(mk & below);
            if (hit && mc + off < MAXC) { cd2[mc + off] = d2; cjj[mc + off] = p; }
            mc += (int)__popcll(mk);
        }
    }
    wsync();
    const int M = min(mc, MAXC);

    // pass 2: 32nd-smallest d2 via per-wave 256-bin histogram
    float thr_d2, thr_w;
    if (M > 32) {
        for (int k = lane; k < M; k += 64)
            atomicAdd(&hist[min(255, (int)(cd2[k] * BUCKSC))], 1);
        wsync();
        int4 h4 = *(const int4*)&hist[lane * 4];
        int hh0 = h4.x, hh1 = h4.y, hh2 = h4.z, hh3 = h4.w;
        int tot = hh0 + hh1 + hh2 + hh3;
        int sc = tot;
        #pragma unroll
        for (int o = 1; o < 64; o <<= 1) {
            int v = __shfl_up(sc, o);
            if (lane >= o) sc += v;
        }
        int ce = sc - tot;                 // exclusive cum at bin 4*lane
        int fb = -1, fce = 0;
        if (ce <= 31 && 31 < ce + hh0) { fb = lane * 4 + 0; fce = ce; } ce += hh0;
        if (fb < 0 && ce <= 31 && 31 < ce + hh1) { fb = lane * 4 + 1; fce = ce; } ce += hh1;
        if (fb < 0 && ce <= 31 && 31 < ce + hh2) { fb = lane * 4 + 2; fce = ce; } ce += hh2;
        if (fb < 0 && ce <= 31 && 31 < ce + hh3) { fb = lane * 4 + 3; fce = ce; }
        unsigned long long mk1 = __ballot(fb >= 0);
        int src1 = (mk1 != 0ull) ? (__ffsll((unsigned long long)mk1) - 1) : 0;
        const int bstar   = __shfl(fb,  src1);
        const int cumexcl = __shfl(fce, src1);
        // gather threshold-bucket members (expected ~1-2)
        int bn = 0;
        for (int k0 = 0; k0 < M; k0 += 64) {
            const int k = k0 + lane;
            bool inb = (k < M) && (min(255, (int)(cd2[k] * BUCKSC)) == bstar);
            unsigned long long mk = __ballot(inb);
            int off = __popcll(mk & below);
            if (inb && bn + off < 32) blist[bn + off] = cd2[k];
            bn += (int)__popcll(mk);
        }
        wsync();
        bn = min(bn, 32);
        float mine = 0.0f; int ok = 0;
        if (lane < bn) {
            mine = blist[lane];
            int cl = 0, ceq = 0;
            for (int m = 0; m < bn; ++m) {
                cl  += (blist[m] <  mine);
                ceq += (blist[m] == mine);
            }
            int r = cumexcl + cl;
            ok = (r <= 31 && 31 < r + ceq);
        }
        unsigned long long mk2 = __ballot(ok);
        int src2 = (mk2 != 0ull) ? (__ffsll((unsigned long long)mk2) - 1) : 0;
        thr_d2 = __shfl(mine, src2);
        thr_w  = expf(-(thr_d2 / 50.0f));  // == ref thresh (weak monotonicity)
    } else {
        thr_d2 = 3.4e38f;                  // ref thresh would be 0 -> keep all
        thr_w  = 0.0f;
    }

    // pass 3: keep w >= thr_w over d2-margin superset (tie-exact);
    // resolve bIdx only for kept lanes (~33 loads/wave).
    const float marg = thr_d2 + 1e-4f;
    int kc = 0;
    for (int k0 = 0; k0 < M; k0 += 64) {
        const int k = k0 + lane;
        bool keep = false; float w = 0.0f; int jj = 0;
        if (k < M && cd2[k] <= marg) {
            w = expf(-(cd2[k] / 50.0f));
            if (w >= thr_w) { keep = true; jj = bIdx[cjj[k]]; }
        }
        unsigned long long mk = __ballot(keep);
        int off = __popcll(mk & below);
        if (keep && kc + off < MAXK)
            kwj[kc + off] = make_float2(w, __int_as_float(jj));
        kc += (int)__popcll(mk);
    }
    wsync();
    const int K = min(kc, MAXK);

    // normalize in registers; lane l holds pair l
    float2 pr = make_float2(0.0f, 0.0f);
    if (lane < K) pr = kwj[lane];
    float v = pr.x;
    #pragma unroll
    for (int o = 32; o > 0; o >>= 1) v += __shfl_xor(v, o);
    const float ssum = fmaxf(v, 1e-8f);    // clip(sum, 1e-8, None)
    const float wn = pr.x / ssum;          // true division as ref
    const int   jn = __float_as_int(pr.y);
    const int   wi = __float_as_int(wn);

    // ---- pass 4 (R8): readlane(k) -> (w,j) in SGPRs, scalar-base addr,
    //      lane = (d-quad, b-pair), 2x dwordx4 + 8 fma per k, unroll 4.
    //      Per-output-element accumulation order (k ascending) == R8.
    const size_t NL = (size_t)N * 64;
    if (TB == 8) {
        const int dq = (lane & 15) * 4;
        const int bp = (lane >> 4) * 2;
        const float* Fb0 = F + (size_t)bp * NL + dq;
        const float* Fb1 = Fb0 + NL;
        float4 a0 = make_float4(0.f, 0.f, 0.f, 0.f);
        float4 a1 = make_float4(0.f, 0.f, 0.f, 0.f);
        #pragma unroll 4
        for (int k = 0; k < K; ++k) {
            const float w = __int_as_float(__builtin_amdgcn_readlane(wi, k));
            const size_t o = (size_t)__builtin_amdgcn_readlane(jn, k) * 64;
            float4 f0 = *(const float4*)(Fb0 + o);
            float4 f1 = *(const float4*)(Fb1 + o);
            a0.x += w * f0.x; a0.y += w * f0.y; a0.z += w * f0.z; a0.w += w * f0.w;
            a1.x += w * f1.x; a1.y += w * f1.y; a1.z += w * f1.z; a1.w += w * f1.w;
        }
        float* O0 = out + (size_t)bp * NL + (size_t)i * 64 + dq;
        *(float4*)O0 = a0;
        *(float4*)(O0 + NL) = a1;
    } else {
        const float* F0 = F + lane;
        float* O0 = out + (size_t)i * 64 + lane;
        for (int b = 0; b < B; ++b) {
            float a = 0.0f;
            const float* Fb = F0 + (size_t)b * NL;
            for (int k = 0; k < K; ++k) {
                const float w = __int_as_float(__builtin_amdgcn_readlane(wi, k));
                const size_t o = (size_t)__builtin_amdgcn_readlane(jn, k) * 64;
                a += w * Fb[o];
            }
            O0[(size_t)b * NL] = a;
        }
    }
}

extern "C" void kernel_launch(void* const* d_in, const int* in_sizes, int n_in,
                              void* d_out, int out_size, void* d_ws, size_t ws_size,
                              hipStream_t stream)
{
    const float* F = (const float*)d_in[0];   // features [B,N,64] f32
    const float* C = (const float*)d_in[1];   // coordinates [N,2] f32
    float* out = (float*)d_out;               // [B,N,64] f32

    const int N = in_sizes[1] / 2;            // 8192
    const int B = in_sizes[0] / (N * 64);     // 8

    // d_ws layout (~97 KB; fully rewritten every call)
    char* ws = (char*)d_ws;
    int*    cellStart = (int*)(ws + 0);                   // NCELL2+1 ints
    float2* bXY       = (float2*)(ws + 512);              // N float2
    int*    bIdx      = (int*)(ws + 512 + (size_t)N * 8); // N ints

    k_prep<<<1, 1024, 0, stream>>>(C, cellStart, bXY, bIdx, N);
    if (N == 8192 && B == 8)
        social_pool_fused<8192, 8><<<2048, 256, 0, stream>>>(
            F, bXY, bIdx, cellStart, out, N, B);
    else
        social_pool_fused<0, 0><<<(N + 3) / 4, 256, 0, stream>>>(
            F, bXY, bIdx, cellStart, out, N, B);
}